// Round 9
// baseline (293.184 us; speedup 1.0000x reference)
//
#include <hip/hip_runtime.h>
#include <math.h>

#define BATCH 1024
#define SEQ   200
#define DIN   128
#define DOUT  128
#define PSTR  608    // partial-delta row stride (floats)

typedef __attribute__((ext_vector_type(8))) short short8;
typedef __attribute__((ext_vector_type(4))) float f32x4;

// async global->LDS, 16B per lane; LDS dest = wave-uniform base + lane*16
__device__ __forceinline__ void async_copy16(const void* g, void* l) {
    __builtin_amdgcn_global_load_lds((const __attribute__((address_space(1))) void*)g,
                                     (__attribute__((address_space(3))) void*)l,
                                     16, 0, 0);
}

__device__ __forceinline__ void split2(float f, short& h, short& l) {
    unsigned u = __float_as_uint(f);
    unsigned r = u + 0x8000u;
    h = (short)(r >> 16);
    float hf = __uint_as_float(r & 0xffff0000u);
    l = (short)(__float_as_uint(f - hf) >> 16);
}

// ---- pre-split S into MFMA B-fragment order (hi at idx, lo at 16384+idx) ----
__global__ __launch_bounds__(256) void k_presplit(const float* __restrict__ S,
                                                  short* __restrict__ Sp) {
    int g = blockIdx.x * 256 + threadIdx.x;          // 0..16383
    int j = g & 7, lane = (g >> 3) & 63, kt = (g >> 9) & 3, nt = g >> 11;
    int k = kt * 32 + (lane >> 4) * 8 + j;
    int n = nt * 16 + (lane & 15);
    short h, l;
    split2(S[k * DOUT + n], h, l);
    Sp[g] = h;
    Sp[16384 + g] = l;
}

// ---- K1: col-split GEMM, ALL A-loads upfront, fp32 output ----
// blockIdx bit0 = col group; block = 128 rows x 64 cols; 32 KB Sp slice in LDS
__global__ __launch_bounds__(256, 4) void k_gemm(const float* __restrict__ A,
                                                 const short* __restrict__ Sp,
                                                 float* __restrict__ outn) {
    __shared__ short sSp[16384];   // hi [0..8191], lo [8192..16383]
    const int t = threadIdx.x;
    const int w = t >> 6, lane = t & 63;
    const int q = lane >> 4, c = lane & 15;
    const int cg = blockIdx.x & 1;
    const long rowb = (long)(blockIdx.x >> 1) * 128 + w * 32;

    // (1) ALL 16 A float4 loads issued first — forces deep MLP
    float4 araw[4][2][2];
#pragma unroll
    for (int kt = 0; kt < 4; ++kt)
#pragma unroll
        for (int mt = 0; mt < 2; ++mt) {
            const float* ap = A + (rowb + mt * 16 + c) * DIN + kt * 32 + q * 8;
            araw[kt][mt][0] = *(const float4*)ap;
            araw[kt][mt][1] = *(const float4*)(ap + 4);
        }

    // (2) async Sp slice: hi chunk + lo chunk (each 16 KB contiguous)
#pragma unroll
    for (int i = 0; i < 4; ++i) {
        const int g = w * 4 + i;
        async_copy16(Sp + cg * 8192 + g * 512 + lane * 8, &sSp[g * 512]);
        async_copy16(Sp + 16384 + cg * 8192 + g * 512 + lane * 8, &sSp[8192 + g * 512]);
    }

    // (3) split A (consumes araw oldest-first while async lands)
    short8 ah[4][2], al[4][2];
#pragma unroll
    for (int kt = 0; kt < 4; ++kt)
#pragma unroll
        for (int mt = 0; mt < 2; ++mt) {
            float av[8];
            *(float4*)&av[0] = araw[kt][mt][0];
            *(float4*)&av[4] = araw[kt][mt][1];
#pragma unroll
            for (int j = 0; j < 8; ++j) {
                short h, l;
                split2(av[j], h, l);
                ah[kt][mt][j] = h; al[kt][mt][j] = l;
            }
        }

    f32x4 acc[2][4];
    const f32x4 zz = {0.f, 0.f, 0.f, 0.f};
#pragma unroll
    for (int mt = 0; mt < 2; ++mt)
#pragma unroll
        for (int nt = 0; nt < 4; ++nt) acc[mt][nt] = zz;

    __syncthreads();   // drains async Sp stage

#pragma unroll
    for (int kt = 0; kt < 4; ++kt)
#pragma unroll
        for (int nt = 0; nt < 4; ++nt) {
            const int fo = ((nt * 4 + kt) * 64 + lane) * 8;
            short8 sh = *(const short8*)&sSp[fo];
            short8 sl = *(const short8*)&sSp[8192 + fo];
#pragma unroll
            for (int mt = 0; mt < 2; ++mt) {
                acc[mt][nt] = __builtin_amdgcn_mfma_f32_16x16x32_bf16(ah[kt][mt], sh, acc[mt][nt], 0, 0, 0);
                acc[mt][nt] = __builtin_amdgcn_mfma_f32_16x16x32_bf16(al[kt][mt], sh, acc[mt][nt], 0, 0, 0);
                acc[mt][nt] = __builtin_amdgcn_mfma_f32_16x16x32_bf16(ah[kt][mt], sl, acc[mt][nt], 0, 0, 0);
            }
        }
    // C/D: col = lane&15, row = (lane>>4)*4 + r
#pragma unroll
    for (int mt = 0; mt < 2; ++mt)
#pragma unroll
        for (int nt = 0; nt < 4; ++nt) {
            const long r0 = rowb + mt * 16 + q * 4;
            const int col = cg * 64 + nt * 16 + c;
#pragma unroll
            for (int r = 0; r < 4; ++r)
                outn[(r0 + r) * DOUT + col] = acc[mt][nt][r];
        }
}

// ---- K2: routing iteration, register-resident slice, no staging barrier ----
// block = (b, e-half); thread t: rows (t>>4)+16i (i<13), cols (t&15)*4 .. +3
__global__ __launch_bounds__(256, 4) void k_iter(
    const float* __restrict__ lown,      // [B][200][128] fp32
    const float* __restrict__ Bm,        // [3][200]
    const int* __restrict__ seq,         // [B]
    const float* __restrict__ acc0, const float* __restrict__ acc1,
    float* __restrict__ part,            // [2048][PSTR]
    float* __restrict__ out, int iter) {
    __shared__ float sW[3][SEQ];         // conflict-free stride 200
    __shared__ f32x4 pBf[815];           // partial h: idx (m*3+k)*17 + cg
    __shared__ float sH[3][64];

    const int t = threadIdx.x, lane = t & 63;
    const int m = t >> 4, cg = t & 15;
    const int b = blockIdx.x >> 1, half = blockIdx.x & 1;
    const float* lp = lown + (size_t)b * (SEQ * DIN) + half * 64;

    // (1) bulk slice loads first: 13 independent coalesced float4
    float4 dat[13];
#pragma unroll
    for (int i = 0; i < 13; ++i) {
        int r = m + 16 * i;
        int rc = (r < SEQ) ? r : SEQ - 1;      // clamp; value unused when r>=SEQ
        dat[i] = *(const float4*)(lp + rc * DIN + cg * 4);
    }

    // (2) redundant per-wave softmax -> no barrier before Pass B
    const int n = seq[b];
#pragma unroll
    for (int k = 0; k < 3; ++k) {
        float vv[4], mx = -INFINITY;
#pragma unroll
        for (int i2 = 0; i2 < 4; ++i2) {
            int l = lane + 64 * i2;
            float v = -INFINITY;
            if (l < n) {                        // l<n implies l<SEQ
                v = Bm[k * SEQ + l];
                if (iter >= 1) v += acc0[k * SEQ + l];
                if (iter >= 2) v += acc1[k * SEQ + l];
            }
            vv[i2] = v;
            mx = fmaxf(mx, v);
        }
        for (int off = 32; off; off >>= 1) mx = fmaxf(mx, __shfl_xor(mx, off, 64));
        float s = 0.f, pv[4];
#pragma unroll
        for (int i2 = 0; i2 < 4; ++i2) {
            pv[i2] = (vv[i2] == -INFINITY) ? 0.f : expf(vv[i2] - mx);
            s += pv[i2];
        }
        for (int off = 32; off; off >>= 1) s += __shfl_xor(s, off, 64);
        float rs = 1.f / s;
#pragma unroll
        for (int i2 = 0; i2 < 4; ++i2) {
            int l = lane + 64 * i2;
            if (l < SEQ) sW[k][l] = pv[i2] * rs;   // identical-value race: benign
        }
    }

    // (3) Pass B: per-thread partials over its rows (reads own wave's sW)
    f32x4 h0 = {0.f, 0.f, 0.f, 0.f}, h1 = h0, h2 = h0;
#pragma unroll
    for (int i = 0; i < 13; ++i) {
        int r = m + 16 * i;
        if (r < SEQ) {
            float w0 = sW[0][r], w1 = sW[1][r], w2 = sW[2][r];
            f32x4 f = {dat[i].x, dat[i].y, dat[i].z, dat[i].w};
            h0 += w0 * f; h1 += w1 * f; h2 += w2 * f;
        }
    }
    pBf[(m * 3 + 0) * 17 + cg] = h0;
    pBf[(m * 3 + 1) * 17 + cg] = h1;
    pBf[(m * 3 + 2) * 17 + cg] = h2;
    __syncthreads();   // B1

    // (4) reduce over the 16 row-classes + squash (threads 0..63, e = t)
    if (t < 64) {
        const int ecg = t >> 2, ej = t & 3;
        float g0 = 0.f, g1 = 0.f, g2 = 0.f;
#pragma unroll
        for (int mm = 0; mm < 16; ++mm) {
            g0 += pBf[(mm * 3 + 0) * 17 + ecg][ej];
            g1 += pBf[(mm * 3 + 1) * 17 + ecg][ej];
            g2 += pBf[(mm * 3 + 2) * 17 + ecg][ej];
        }
        float sq = g0 * g0 + g1 * g1 + g2 * g2;
        float scale = sq / (1.f + sq) / sqrtf(sq + 1e-9f);
        g0 *= scale; g1 *= scale; g2 *= scale;
        if (iter == 2) {
            size_t o = (size_t)b * 3 * DOUT + half * 64 + t;
            out[o] = g0; out[o + DOUT] = g1; out[o + 2 * DOUT] = g2;
        } else {
            sH[0][t] = g0; sH[1][t] = g1; sH[2][t] = g2;
        }
    }
    if (iter == 2) return;   // uniform exit
    __syncthreads();   // B2

    // (5) Pass C: per-row dot over this thread's 4 cols, shuffle-reduce over 16
    f32x4 x0 = *(const f32x4*)&sH[0][cg * 4];
    f32x4 x1 = *(const f32x4*)&sH[1][cg * 4];
    f32x4 x2 = *(const f32x4*)&sH[2][cg * 4];
    float* pp = part + (size_t)blockIdx.x * PSTR;
#pragma unroll
    for (int i = 0; i < 13; ++i) {
        int r = m + 16 * i;
        if (r < SEQ) {
            f32x4 f = {dat[i].x, dat[i].y, dat[i].z, dat[i].w};
            f32x4 p0 = x0 * f, p1 = x1 * f, p2 = x2 * f;
            float d0 = p0[0] + p0[1] + p0[2] + p0[3];
            float d1 = p1[0] + p1[1] + p1[2] + p1[3];
            float d2 = p2[0] + p2[1] + p2[2] + p2[3];
#pragma unroll
            for (int off = 1; off < 16; off <<= 1) {   // reduce over cg (lane bits 0-3)
                d0 += __shfl_xor(d0, off, 64);
                d1 += __shfl_xor(d1, off, 64);
                d2 += __shfl_xor(d2, off, 64);
            }
            if (cg == 0) {
                pp[r] = d0; pp[SEQ + r] = d1; pp[2 * SEQ + r] = d2;
            }
        }
    }
}

// ---- K3: band-sum part[2048][PSTR] -> accN[600]; 128 blocks x 16 rows ----
__global__ __launch_bounds__(256) void k_reduce(const float* __restrict__ part,
                                                float* __restrict__ accN) {
    const int t = threadIdx.x;
    const int r0 = blockIdx.x * 16;
    if (t < 150) {
        float sx = 0.f, sy = 0.f, sz = 0.f, sw = 0.f;
#pragma unroll
        for (int r = 0; r < 16; ++r) {
            float4 v = *(const float4*)&part[(size_t)(r0 + r) * PSTR + t * 4];
            sx += v.x; sy += v.y; sz += v.z; sw += v.w;
        }
        atomicAdd(&accN[4 * t + 0], sx);
        atomicAdd(&accN[4 * t + 1], sy);
        atomicAdd(&accN[4 * t + 2], sz);
        atomicAdd(&accN[4 * t + 3], sw);
    }
}

extern "C" void kernel_launch(void* const* d_in, const int* in_sizes, int n_in,
                              void* d_out, int out_size, void* d_ws, size_t ws_size,
                              hipStream_t stream) {
    const float* low_capsule = (const float*)d_in[0];   // [1024][200][128]
    const float* B_matrix    = (const float*)d_in[1];   // [1][3][200]
    const float* S_matrix    = (const float*)d_in[2];   // [128][128]
    const int*   seq_len     = (const int*)d_in[3];     // [1024]
    float* out = (float*)d_out;                         // [1024][3][128]

    float* lown = (float*)d_ws;                                // 26,214,400 f32
    short* Sp   = (short*)(lown + (size_t)BATCH * SEQ * DOUT); // 32768 shorts
    float* acc0 = (float*)(Sp + 32768);                        // 600 (pad 640)
    float* acc1 = acc0 + 640;                                  // 600 (pad 640)
    float* part = acc1 + 640;                                  // 2048 * PSTR

    hipMemsetAsync(acc0, 0, 1280 * sizeof(float), stream);

    k_presplit<<<64, 256, 0, stream>>>(S_matrix, Sp);
    k_gemm<<<2 * (BATCH * SEQ) / 128, 256, 0, stream>>>(low_capsule, Sp, lown);

    k_iter<<<2 * BATCH, 256, 0, stream>>>(lown, B_matrix, seq_len, acc0, acc1, part, out, 0);
    k_reduce<<<128, 256, 0, stream>>>(part, acc0);
    k_iter<<<2 * BATCH, 256, 0, stream>>>(lown, B_matrix, seq_len, acc0, acc1, part, out, 1);
    k_reduce<<<128, 256, 0, stream>>>(part, acc1);
    k_iter<<<2 * BATCH, 256, 0, stream>>>(lown, B_matrix, seq_len, acc0, acc1, part, out, 2);
}

// Round 11
// 288.301 us; speedup vs baseline: 1.0169x; 1.0169x over previous
//
#include <hip/hip_runtime.h>
#include <math.h>

#define BATCH 1024
#define SEQ   200
#define DIN   128
#define DOUT  128
#define SSTR  129    // S LDS row stride: odd -> (d+e)%32 banking, both dot phases conflict-free
#define PSTR  608    // partial-delta row stride (floats)

typedef __attribute__((ext_vector_type(4))) float f32x4;

// ---- K2: one routing iteration, low_new eliminated via y=W*low, z=S*high ----
// block = one batch b, 512 threads; slice register-resident; S in LDS
__global__ __launch_bounds__(512, 1) void k_iter(
    const float* __restrict__ low,       // [B][200][128] raw input
    const float* __restrict__ S,         // [128][128]
    const float* __restrict__ Bm,        // [3][200]
    const int* __restrict__ seq,         // [B]
    const float* __restrict__ acc0, const float* __restrict__ acc1,
    float* __restrict__ part,            // [1024][PSTR]
    float* __restrict__ out, int iter) {
    __shared__ float sS[128 * SSTR];     // 66 KB, stride-129
    __shared__ float sW[3 * SEQ];
    __shared__ f32x4 pY[8][3][32];       // per-wave pass-B partials
    __shared__ float sY[3 * 128];        // y[k][d]
    __shared__ float sHp[3 * 128];       // high_pre[k][e] (unscaled)
    __shared__ float sH[3 * 128];        // high[k][e] (scaled)
    __shared__ float sZ[3 * 128];        // z[k][d]

    const int t = threadIdx.x, lane = t & 63, w = t >> 6;
    const int m = t >> 5, cg = t & 31;   // rows m+16i, cols cg*4..+3
    const int b = blockIdx.x;
    const float* lp = low + (size_t)b * (SEQ * DIN);

    // (1) softmax raw loads first (small, L2-hot, waves 0-2)
    float r0[4], r1[4], r2[4];
    if (w < 3) {
#pragma unroll
        for (int i = 0; i < 4; ++i) {
            int l = lane + 64 * i; bool inb = l < SEQ;
            r0[i] = inb ? Bm[w * SEQ + l] : 0.f;
            r1[i] = (inb && iter >= 1) ? acc0[w * SEQ + l] : 0.f;
            r2[i] = (inb && iter >= 2) ? acc1[w * SEQ + l] : 0.f;
        }
    }

    // (2) slice loads: 13 independent coalesced float4 per thread
    float4 dat[13];
#pragma unroll
    for (int i = 0; i < 13; ++i) {
        int r = m + 16 * i;
        int rc = (r < SEQ) ? r : SEQ - 1;
        dat[i] = *(const float4*)(lp + rc * DIN + cg * 4);
    }

    // (3) stage S into LDS (stride 129): 8 coalesced float4 reads/thread
#pragma unroll
    for (int i = 0; i < 8; ++i) {
        int g = t + 512 * i;             // float4 id, 0..4095
        int r = g >> 5, e = (g & 31) * 4;
        float4 v = *(const float4*)(S + r * DIN + e);
        sS[r * SSTR + e + 0] = v.x;
        sS[r * SSTR + e + 1] = v.y;
        sS[r * SSTR + e + 2] = v.z;
        sS[r * SSTR + e + 3] = v.w;
    }

    // (4) softmax compute (waves 0-2, k = wave)
    if (w < 3) {
        const int n = seq[b];
        float mx = -INFINITY, vv[4];
#pragma unroll
        for (int i = 0; i < 4; ++i) {
            int l = lane + 64 * i;
            float v = r0[i] + r1[i] + r2[i];
            vv[i] = (l < n) ? v : -INFINITY;
            if (l < n) mx = fmaxf(mx, v);
        }
        for (int off = 32; off; off >>= 1) mx = fmaxf(mx, __shfl_xor(mx, off, 64));
        float s = 0.f, pv[4];
#pragma unroll
        for (int i = 0; i < 4; ++i) {
            pv[i] = (vv[i] == -INFINITY) ? 0.f : expf(vv[i] - mx);
            s += pv[i];
        }
        for (int off = 32; off; off >>= 1) s += __shfl_xor(s, off, 64);
        float rs = 1.f / s;
#pragma unroll
        for (int i = 0; i < 4; ++i) {
            int l = lane + 64 * i;
            if (l < SEQ) sW[w * SEQ + l] = pv[i] * rs;
        }
    }
    __syncthreads();   // B1: sW + sS ready

    // (5) Pass B: y-partials over this thread's rows, reduce over m-parity
    {
        f32x4 h0 = {0.f, 0.f, 0.f, 0.f}, h1 = h0, h2 = h0;
#pragma unroll
        for (int i = 0; i < 13; ++i) {
            int r = m + 16 * i;
            if (r < SEQ) {
                float w0 = sW[r], w1 = sW[SEQ + r], w2 = sW[2 * SEQ + r];
                f32x4 f = {dat[i].x, dat[i].y, dat[i].z, dat[i].w};
                h0 += w0 * f; h1 += w1 * f; h2 += w2 * f;
            }
        }
#pragma unroll
        for (int c = 0; c < 4; ++c) {    // reduce over lane bit 5 (m parity)
            h0[c] += __shfl_xor(h0[c], 32, 64);
            h1[c] += __shfl_xor(h1[c], 32, 64);
            h2[c] += __shfl_xor(h2[c], 32, 64);
        }
        if (lane < 32) { pY[w][0][cg] = h0; pY[w][1][cg] = h1; pY[w][2][cg] = h2; }
    }
    __syncthreads();   // B2

    // (6) y assemble: thread (k = t>>7, d = t&127) for t < 384
    if (t < 384) {
        const int k = t >> 7, d = t & 127;
        float yv = 0.f;
#pragma unroll
        for (int w8 = 0; w8 < 8; ++w8)
            yv += pY[w8][k][d >> 2][d & 3];
        sY[k * 128 + d] = yv;
    }
    __syncthreads();   // B3

    // (7) high_pre[k,e] = y_k . S[:,e]
    float hval = 0.f;
    if (t < 384) {
        const int k = t >> 7, e = t & 127;
        float hp = 0.f;
        for (int d = 0; d < 128; ++d)
            hp = fmaf(sY[k * 128 + d], sS[d * SSTR + e], hp);   // y broadcast; S 2-way banks
        hval = hp;
        sHp[t] = hp;
    }
    __syncthreads();   // B4

    // squash: per-e scale = f(sum_k high_pre[k,e]^2)  [k-axis reduction only!]
    float scale = 0.f;
    if (t < 384) {
        const int e = t & 127;
        float g0 = sHp[e], g1 = sHp[128 + e], g2 = sHp[256 + e];
        float sq = g0 * g0 + g1 * g1 + g2 * g2;
        scale = sq / (1.f + sq) / sqrtf(sq + 1e-9f);
    }

    if (iter == 2) {   // final: write high, done (uniform exit)
        if (t < 384) out[(size_t)b * 384 + t] = hval * scale;
        return;
    }
    if (t < 384) sH[t] = hval * scale;
    __syncthreads();   // B5

    // (8) z[k,d] = S[d,:] . high_k  (sH broadcast; S (d+e)%32 = 2-way free)
    if (t < 384) {
        const int k = t >> 7, d = t & 127;
        float zv = 0.f;
        for (int e = 0; e < 128; ++e)
            zv = fmaf(sS[d * SSTR + e], sH[k * 128 + e], zv);
        sZ[k * 128 + d] = zv;
    }
    __syncthreads();   // B6

    // (9) Pass C: delta[k,r] = z_k . low[r] over register slice
    {
        f32x4 x0 = *(const f32x4*)&sZ[0 * 128 + cg * 4];
        f32x4 x1 = *(const f32x4*)&sZ[1 * 128 + cg * 4];
        f32x4 x2 = *(const f32x4*)&sZ[2 * 128 + cg * 4];
        float* pp = part + (size_t)b * PSTR;
#pragma unroll
        for (int i = 0; i < 13; ++i) {
            int r = m + 16 * i;
            if (r < SEQ) {
                f32x4 f = {dat[i].x, dat[i].y, dat[i].z, dat[i].w};
                f32x4 p0 = x0 * f, p1 = x1 * f, p2 = x2 * f;
                float d0 = p0[0] + p0[1] + p0[2] + p0[3];
                float d1 = p1[0] + p1[1] + p1[2] + p1[3];
                float d2 = p2[0] + p2[1] + p2[2] + p2[3];
#pragma unroll
                for (int off = 1; off < 32; off <<= 1) {   // reduce over cg (lane bits 0-4)
                    d0 += __shfl_xor(d0, off, 64);
                    d1 += __shfl_xor(d1, off, 64);
                    d2 += __shfl_xor(d2, off, 64);
                }
                if ((lane & 31) == 0) {
                    pp[r] = d0; pp[SEQ + r] = d1; pp[2 * SEQ + r] = d2;
                }
            }
        }
    }
}

// ---- K3: band-sum part[1024][PSTR] -> accN[600]; 64 blocks x 16 rows ----
__global__ __launch_bounds__(256) void k_reduce(const float* __restrict__ part,
                                                float* __restrict__ accN) {
    const int t = threadIdx.x;
    const int r0 = blockIdx.x * 16;
    if (t < 150) {
        float sx = 0.f, sy = 0.f, sz = 0.f, sw = 0.f;
#pragma unroll
        for (int r = 0; r < 16; ++r) {
            float4 v = *(const float4*)&part[(size_t)(r0 + r) * PSTR + t * 4];
            sx += v.x; sy += v.y; sz += v.z; sw += v.w;
        }
        atomicAdd(&accN[4 * t + 0], sx);
        atomicAdd(&accN[4 * t + 1], sy);
        atomicAdd(&accN[4 * t + 2], sz);
        atomicAdd(&accN[4 * t + 3], sw);
    }
}

extern "C" void kernel_launch(void* const* d_in, const int* in_sizes, int n_in,
                              void* d_out, int out_size, void* d_ws, size_t ws_size,
                              hipStream_t stream) {
    const float* low_capsule = (const float*)d_in[0];   // [1024][200][128]
    const float* B_matrix    = (const float*)d_in[1];   // [1][3][200]
    const float* S_matrix    = (const float*)d_in[2];   // [128][128]
    const int*   seq_len     = (const int*)d_in[3];     // [1024]
    float* out = (float*)d_out;                         // [1024][3][128]

    float* acc0 = (float*)d_ws;                         // 600 (pad 640)
    float* acc1 = acc0 + 640;                           // 600 (pad 640)
    float* part = acc1 + 640;                           // 1024 * PSTR

    hipMemsetAsync(acc0, 0, 1280 * sizeof(float), stream);

    k_iter<<<BATCH, 512, 0, stream>>>(low_capsule, S_matrix, B_matrix, seq_len,
                                      acc0, acc1, part, out, 0);
    k_reduce<<<64, 256, 0, stream>>>(part, acc0);
    k_iter<<<BATCH, 512, 0, stream>>>(low_capsule, S_matrix, B_matrix, seq_len,
                                      acc0, acc1, part, out, 1);
    k_reduce<<<64, 256, 0, stream>>>(part, acc1);
    k_iter<<<BATCH, 512, 0, stream>>>(low_capsule, S_matrix, B_matrix, seq_len,
                                      acc0, acc1, part, out, 2);
}